// Round 13
// baseline (3339.054 us; speedup 1.0000x reference)
//
#include <hip/hip_runtime.h>
#include <hip/hip_bf16.h>

// PeepholeLSTM: SEQ=512, BATCH=64, IN=512, HS=1024, FORGET_BIAS=0
// out = [hidden_seq (512*64*1024) | c_T (64*1024) | h_T (64*1024)] f32
//
// Round-13: fused config (pc=32, NWG=128) + PER-GROUP gate + DEPTH=64.
//   r9: no gate -> consumer races poison L2 -> all traffic on LLC bypass (6.3TB/s wall).
//   r12: global gate but DEPTH=16 -> stale L2 lines survive -> tags catch -> bypass
//   anyway, plus global-convoy cost. Fix needs BOTH: DEPTH=64 (stale slot lines
//   certainly evicted between reuses: 16MB churn > 4MB L2) AND a gate so plain loads
//   only issue after data is at the LLC. Gate is per consume-GROUP (group G reads only
//   source WGs 32G..32G+31): lanes 0..31 poll 32 gate words sc0sc1 + sleep backoff,
//   then group G's plain loads miss L2 and fill FRESH -> shared by the XCD's 16 WGs.
//   Embedded tags remain the correctness net (stale survivor -> sc0sc1 retry).
//   Producer: per-wave publish exchanges -> vmcnt(0) -> LDS fan-in -> 4th wave writes
//   gate word (own 64B line). No __syncthreads in the step loop.

#define SEQN 512
#define BATCH 64
#define INDIM 512
#define HSZ 1024
#define NWG 128
#define DEPTH 64

typedef __attribute__((ext_vector_type(8))) short s16x8;
typedef __attribute__((ext_vector_type(4))) float f32x4;
typedef __attribute__((ext_vector_type(2))) float f32x2;
typedef __attribute__((ext_vector_type(4))) int i32x4;
typedef unsigned long long u64;

__device__ __forceinline__ short f2bf(float f) {
  __hip_bfloat16 b = __float2bfloat16(f);
  short s;
  __builtin_memcpy(&s, &b, 2);
  return s;
}
__device__ __forceinline__ float sigf(float x) { return 1.f / (1.f + __expf(-x)); }
__device__ __forceinline__ float tanh_fast(float x) { return 2.f / (1.f + __expf(-2.f * x)) - 1.f; }

// ---------------------------------------------------------------------------
// prep_w: col = gate*1024 + hidx; hidx = g*8+off; pc = off*4+gate.
__global__ __launch_bounds__(256) void prep_w(const float* __restrict__ W,
                                              short* __restrict__ WxP,
                                              short* __restrict__ WhP) {
  int idx = blockIdx.x * 256 + threadIdx.x;
  if (idx >= 1536 * 4096) return;
  int k = idx >> 12, col = idx & 4095;
  short b = f2bf(W[idx]);
  int gate = col >> 10, hidx = col & 1023;
  int g = hidx >> 3, off = hidx & 7;
  int pc = off * 4 + gate;
  if (k < 512) {
    WxP[(size_t)(((g * 64 + (k >> 3)) * 32 + pc) << 3) + (k & 7)] = b;
  } else {
    int kh = k - 512;
    WhP[(size_t)(((g * 128 + (kh >> 3)) * 32 + pc) << 3) + (kh & 7)] = b;
  }
}

// ---------------------------------------------------------------------------
// prep_x: x[t][m][k] f32 -> xbp[t][kb][m][8] bf16.
__global__ __launch_bounds__(256) void prep_x(const float* __restrict__ x,
                                              short* __restrict__ xbp) {
  int idx = blockIdx.x * 256 + threadIdx.x;
  if (idx >= SEQN * 64 * 64) return;
  int kb = idx & 63, m = (idx >> 6) & 63, t = idx >> 12;
  const float4* xp = reinterpret_cast<const float4*>(x + ((size_t)t * 64 + m) * 512 + kb * 8);
  float4 a = xp[0], c = xp[1];
  s16x8 v;
  v[0] = f2bf(a.x); v[1] = f2bf(a.y); v[2] = f2bf(a.z); v[3] = f2bf(a.w);
  v[4] = f2bf(c.x); v[5] = f2bf(c.y); v[6] = f2bf(c.z); v[7] = f2bf(c.w);
  reinterpret_cast<s16x8*>(xbp)[((size_t)t * 64 + kb) * 64 + m] = v;
}

// ---------------------------------------------------------------------------
// lstm_seq: 128 WGs x 256. WG g: hidden [8g,8g+8). Wave w: batch rows [16w,16w+16).
// Lane l: m = w*16+(l&15), q4 = l>>4, hidden cols c0 = 8g+q4, c1 = c0+4, all 4 gates.
// hqt[t&63][gsrc 128][m 64][j 4] u64 = tag(t)<<32 | h[8gsrc+j+4]<<16 | h[8gsrc+j].
// gates[t&63][g 128] u64 (stride 8 u64 = one 64B line each): == t when producer g's
// step-(t-1) h is acked at the LLC.
__global__ __launch_bounds__(256, 1) void lstm_seq(const short* __restrict__ xbp,
                                                   const short* __restrict__ WhP,
                                                   const short* __restrict__ WxP,
                                                   const float* __restrict__ bias,
                                                   const float* __restrict__ peep_i,
                                                   const float* __restrict__ peep_f,
                                                   const float* __restrict__ peep_o,
                                                   u64* hqt,
                                                   u64* gates,
                                                   float* __restrict__ out) {
  __shared__ short WhS[32768];   // 64KB [kb 128][pc 32][8]
  __shared__ short WxS[16384];   // 32KB [kb  64][pc 32][8]
  __shared__ float outS[512];    //  2KB
  __shared__ unsigned ctrS;      // monotonic wave-completion counter
  int g = blockIdx.x;
  int tid = threadIdx.x, w = tid >> 6, l = tid & 63;
  {
    const s16x8* src = reinterpret_cast<const s16x8*>(WhP + (size_t)g * 32768);
    s16x8* dst = reinterpret_cast<s16x8*>(WhS);
#pragma unroll
    for (int i = 0; i < 16; ++i) dst[i * 256 + tid] = src[i * 256 + tid];
    const s16x8* src2 = reinterpret_cast<const s16x8*>(WxP + (size_t)g * 16384);
    s16x8* dst2 = reinterpret_cast<s16x8*>(WxS);
#pragma unroll
    for (int i = 0; i < 8; ++i) dst2[i * 256 + tid] = src2[i * 256 + tid];
  }
  if (tid == 0) ctrS = 0;
  int m = w * 16 + (l & 15), q4 = l >> 4, l15 = l & 15;
  int c0 = g * 8 + q4, c1 = c0 + 4;
  float bi0 = bias[c0], bj0 = bias[1024 + c0], bf0 = bias[2048 + c0], bo0 = bias[3072 + c0];
  float bi1 = bias[c1], bj1 = bias[1024 + c1], bf1 = bias[2048 + c1], bo1 = bias[3072 + c1];
  float pi0 = peep_i[c0], pf0 = peep_f[c0], po0 = peep_o[c0];
  float pi1 = peep_i[c1], pf1 = peep_f[c1], po1 = peep_o[c1];
  float cr0 = 0.f, cr1 = 0.f;
  s16x8* WhS16 = reinterpret_cast<s16x8*>(WhS);
  s16x8* WxS16 = reinterpret_cast<s16x8*>(WxS);
  __syncthreads();

// per-group gate: group G consumes WGs 32G..32G+31. Lanes poll those 32 gate words
// (sc0sc1 = fresh at LLC) until all == t. Backoff via s_sleep.
#define GATEW(G)                                                                         \
  {                                                                                      \
    const u64* gp_ = gq + (size_t)((G) * 32 + (l & 31)) * 8;                             \
    int guard = 0;                                                                       \
    while (true) {                                                                       \
      u64 v_;                                                                            \
      asm volatile("global_load_dwordx2 %0, %1, off sc0 sc1" : "=v"(v_) : "v"(gp_));     \
      asm volatile("s_waitcnt vmcnt(0)" ::: "memory");                                   \
      __builtin_amdgcn_sched_barrier(0);                                                 \
      if (__all((int)(v_ == (u64)(unsigned)t))) break;                                   \
      if (++guard > (1 << 15)) break; /* fail loud (tags still verify), never hang */    \
      __builtin_amdgcn_s_sleep(1);                                                       \
    }                                                                                    \
  }
// group G: 16 dwordx4/lane (= 32 tagged u64, 8 kb-blocks). PLAIN loads: gate guarantees
// freshness at LLC; DEPTH=64 guarantees no stale L2 residency -> miss+fill, shared by
// the XCD's 16 WGs. Tags = correctness net only.
#define LOADG(BANK, G)                                                                   \
  {                                                                                      \
    _Pragma("unroll") for (int i = 0; i < 16; ++i) {                                     \
      int kb_ = ((G) * 8 + (i >> 1)) * 4 + q4;                                           \
      BANK[i] = *reinterpret_cast<const i32x4*>(rdq + kb_ * 256 + m * 4 + (i & 1) * 2);  \
    }                                                                                    \
  }
// rare retry (stale L2 survivor): bypass L1+L2, fresh at LLC
#define RELOADG(BANK, G)                                                                 \
  {                                                                                      \
    _Pragma("unroll") for (int i = 0; i < 16; ++i) {                                     \
      int kb_ = ((G) * 8 + (i >> 1)) * 4 + q4;                                           \
      const u64* p_ = rdq + kb_ * 256 + m * 4 + (i & 1) * 2;                             \
      asm volatile("global_load_dwordx4 %0, %1, off sc0 sc1" : "=v"(BANK[i]) : "v"(p_)); \
    }                                                                                    \
    asm volatile("s_waitcnt vmcnt(0)" ::: "memory");                                     \
    __builtin_amdgcn_sched_barrier(0);                                                   \
  }
#define CHECKG(BANK, G)                                                                  \
  {                                                                                      \
    int guard = 0;                                                                       \
    while (true) {                                                                       \
      bool ok = true;                                                                    \
      _Pragma("unroll") for (int i = 0; i < 16; ++i) ok &=                               \
          ((unsigned)BANK[i][1] == (unsigned)t) & ((unsigned)BANK[i][3] == (unsigned)t); \
      if (__all((int)ok)) break;                                                         \
      if (++guard > (1 << 13)) break; /* fail loud, never hang */                        \
      RELOADG(BANK, G);                                                                  \
    }                                                                                    \
  }
#define MFMAG(BANK, G)                                                                   \
  {                                                                                      \
    _Pragma("unroll") for (int kk2 = 0; kk2 < 8; ++kk2) {                                \
      int kb_ = ((G) * 8 + kk2) * 4 + q4;                                                \
      unsigned d0 = (unsigned)BANK[kk2 * 2][0], d1 = (unsigned)BANK[kk2 * 2][2];         \
      unsigned d2 = (unsigned)BANK[kk2 * 2 + 1][0], d3 = (unsigned)BANK[kk2 * 2 + 1][2]; \
      union { unsigned u[4]; s16x8 v; } bu;                                              \
      bu.u[0] = (d0 & 0xFFFFu) | (d1 << 16);                                             \
      bu.u[1] = (d2 & 0xFFFFu) | (d3 << 16);                                             \
      bu.u[2] = (d0 >> 16) | (d1 & 0xFFFF0000u);                                         \
      bu.u[3] = (d2 >> 16) | (d3 & 0xFFFF0000u);                                        \
      s16x8 a0 = WhS16[kb_ * 32 + l15];                                                  \
      s16x8 a1 = WhS16[kb_ * 32 + 16 + l15];                                             \
      acc0 = __builtin_amdgcn_mfma_f32_16x16x32_bf16(a0, bu.v, acc0, 0, 0, 0);           \
      acc1 = __builtin_amdgcn_mfma_f32_16x16x32_bf16(a1, bu.v, acc1, 0, 0, 0);           \
    }                                                                                    \
  }

  for (int t = 0; t < SEQN; ++t) {
    f32x4 acc0 = {0.f, 0.f, 0.f, 0.f}, acc1 = {0.f, 0.f, 0.f, 0.f};
    // ---- x-projection (h-independent; fills producer-publish window) ----
    {
      const s16x8* xt = reinterpret_cast<const s16x8*>(xbp) + (size_t)t * 4096;
#pragma unroll 4
      for (int kk = 0; kk < 16; ++kk) {
        int kb = kk * 4 + q4;
        s16x8 bx = xt[kb * 64 + m];
        s16x8 a0 = WxS16[kb * 32 + l15];
        s16x8 a1 = WxS16[kb * 32 + 16 + l15];
        acc0 = __builtin_amdgcn_mfma_f32_16x16x32_bf16(a0, bx, acc0, 0, 0, 0);
        acc1 = __builtin_amdgcn_mfma_f32_16x16x32_bf16(a1, bx, acc1, 0, 0, 0);
      }
    }
    if (t > 0) {
      const u64* rdq = hqt + (size_t)(t & (DEPTH - 1)) * 32768;
      const u64* gq = gates + (size_t)(t & (DEPTH - 1)) * 1024;
      // ---- consume: per-group gate -> plain load -> tag check -> MFMA, pipelined ----
      i32x4 hA[16], hB[16];
      GATEW(0);
      LOADG(hA, 0);
      GATEW(1);
      LOADG(hB, 1);
      CHECKG(hA, 0);
      MFMAG(hA, 0);
      GATEW(2);
      LOADG(hA, 2);
      CHECKG(hB, 1);
      MFMAG(hB, 1);
      GATEW(3);
      LOADG(hB, 3);
      CHECKG(hA, 2);
      MFMAG(hA, 2);
      CHECKG(hB, 3);
      MFMAG(hB, 3);
    }
    // ---- elementwise (lane-local: all 4 gates of c0 and c1) ----
    float i0 = sigf(acc0[0] + bi0 + cr0 * pi0);
    float f0 = sigf(acc0[2] + bf0 + cr0 * pf0);
    float cn0 = f0 * cr0 + i0 * tanh_fast(acc0[1] + bj0);
    float o0 = sigf(acc0[3] + bo0 + cn0 * po0);
    float h0 = o0 * tanh_fast(cn0);
    cr0 = cn0;
    float i1 = sigf(acc1[0] + bi1 + cr1 * pi1);
    float f1 = sigf(acc1[2] + bf1 + cr1 * pf1);
    float cn1 = f1 * cr1 + i1 * tanh_fast(acc1[1] + bj1);
    float o1 = sigf(acc1[3] + bo1 + cn1 * po1);
    float h1 = o1 * tanh_fast(cn1);
    cr1 = cn1;
    // ---- publish tagged h_t (tag t+1) -> drain -> per-WG gate fan-in ----
    {
      u64 q = ((u64)(unsigned)(t + 1) << 32) |
              ((u64)(unsigned short)f2bf(h1) << 16) | (u64)(unsigned short)f2bf(h0);
      (void)__hip_atomic_exchange(
          hqt + (size_t)((t + 1) & (DEPTH - 1)) * 32768 + g * 256 + m * 4 + q4, q,
          __ATOMIC_RELAXED, __HIP_MEMORY_SCOPE_AGENT);
    }
    asm volatile("s_waitcnt vmcnt(0)" ::: "memory");  // data acked at LLC
    if (l == 0) {
      unsigned old = atomicAdd(&ctrS, 1u);  // LDS, monotonic (4 waves per step)
      if (old == 4u * (unsigned)t + 3u) {   // last wave of this WG this step
        (void)__hip_atomic_exchange(
            gates + (size_t)((t + 1) & (DEPTH - 1)) * 1024 + (size_t)g * 8,
            (u64)(unsigned)(t + 1), __ATOMIC_RELAXED, __HIP_MEMORY_SCOPE_AGENT);
      }
    }
    // ---- coalesced hidden_seq store via wave-local LDS stage ----
    outS[w * 128 + l15 * 8 + q4] = h0;
    outS[w * 128 + l15 * 8 + q4 + 4] = h1;
    {
      f32x2 v = *reinterpret_cast<f32x2*>(&outS[w * 128 + (l >> 2) * 8 + (l & 3) * 2]);
      int row = w * 16 + (l >> 2), col = g * 8 + (l & 3) * 2;
      __builtin_nontemporal_store(
          v, reinterpret_cast<f32x2*>(out + (size_t)t * 65536 + (size_t)row * 1024 + col));
    }
    if (t == SEQN - 1) {
      out[33554432ull + (size_t)m * 1024 + c0] = cn0;  // c_T
      out[33554432ull + (size_t)m * 1024 + c1] = cn1;
      out[33619968ull + (size_t)m * 1024 + c0] = h0;   // h_T
      out[33619968ull + (size_t)m * 1024 + c1] = h1;
    }
  }
#undef GATEW
#undef LOADG
#undef RELOADG
#undef CHECKG
#undef MFMAG
}

// ---------------------------------------------------------------------------
extern "C" void kernel_launch(void* const* d_in, const int* in_sizes, int n_in,
                              void* d_out, int out_size, void* d_ws, size_t ws_size,
                              hipStream_t stream) {
  const float* x      = (const float*)d_in[0];
  const float* W      = (const float*)d_in[1];
  const float* bias   = (const float*)d_in[2];
  const float* peep_i = (const float*)d_in[3];
  const float* peep_f = (const float*)d_in[4];
  const float* peep_o = (const float*)d_in[5];
  char* ws = (char*)d_ws;
  short* WxP = (short*)(ws);                   //  4194304 B
  short* WhP = (short*)(ws + 4194304ull);      //  8388608 B
  short* xbp = (short*)(ws + 12582912ull);     // 33554432 B
  u64* hqt   = (u64*)(ws + 46137344ull);       // 16777216 B (64 x 256KB tagged h slots)
  u64* gates = (u64*)(ws + 62914560ull);       //   524288 B (64 x 8KB gate slots)
  // zero tags+gates every launch: stale values from a prior replay must never alias
  // this run's expected tag sequence (hqt and gates contiguous: one memset)
  (void)hipMemsetAsync(hqt, 0, 17301504ull, stream);
  prep_w<<<24576, 256, 0, stream>>>(W, WxP, WhP);
  prep_x<<<8192, 256, 0, stream>>>(x, xbp);
  lstm_seq<<<NWG, 256, 0, stream>>>(xbp, WhP, WxP, bias, peep_i, peep_f, peep_o, hqt,
                                    gates, (float*)d_out);
}

// Round 14
// 2139.856 us; speedup vs baseline: 1.5604x; 1.5604x over previous
//
#include <hip/hip_runtime.h>
#include <hip/hip_bf16.h>

// PeepholeLSTM: SEQ=512, BATCH=64, IN=512, HS=1024, FORGET_BIAS=0
// out = [hidden_seq (512*64*1024) | c_T (64*1024) | h_T (64*1024)] f32
//
// Round-14: TAG-FREE payload + per-wave seqlock gate. (pc=32, NWG=128, fused x-proj.)
//   r9 (best, 5.1us/step): optimistic tagged u64s -> HALF the 32MB/step LLC volume was
//   tags, plus retry re-reads + repack VALU. r12/r13 gates failed because their payload
//   was still tagged+plain+poisoned. This round: payload = pure 4xbf16 u64 (16MB/step),
//   publish = exchanges -> vmcnt(0) -> ONE tag word per (WG,wave) [seqlock: data acked
//   at LLC before tag visible]. Consumer: poll its 128 tags (1 dwordx4/lane sc0sc1 +
//   sleep), then SINGLE-SHOT sc0sc1 payload loads (in-order issue after observed tag
//   => LLC copy current; no checks, no retries). Payload dwordx4 = exact MFMA B-frag
//   (no repack). Counted vmcnt(8) pipeline (all-asm region, counts exact; rule #18
//   sched_barrier after each wait). DEPTH=4 (gate bounds skew to 1 step).

#define SEQN 512
#define BATCH 64
#define INDIM 512
#define HSZ 1024
#define NWG 128
#define DEPTH 4

typedef __attribute__((ext_vector_type(8))) short s16x8;
typedef __attribute__((ext_vector_type(4))) float f32x4;
typedef __attribute__((ext_vector_type(2))) float f32x2;
typedef __attribute__((ext_vector_type(4))) int i32x4;
typedef unsigned long long u64;

__device__ __forceinline__ short f2bf(float f) {
  __hip_bfloat16 b = __float2bfloat16(f);
  short s;
  __builtin_memcpy(&s, &b, 2);
  return s;
}
__device__ __forceinline__ float sigf(float x) { return 1.f / (1.f + __expf(-x)); }
__device__ __forceinline__ float tanh_fast(float x) { return 2.f / (1.f + __expf(-2.f * x)) - 1.f; }

// ---------------------------------------------------------------------------
// prep_w: col = gate*1024 + hidx; hidx = g*8+off; pc = off*4+gate.
__global__ __launch_bounds__(256) void prep_w(const float* __restrict__ W,
                                              short* __restrict__ WxP,
                                              short* __restrict__ WhP) {
  int idx = blockIdx.x * 256 + threadIdx.x;
  if (idx >= 1536 * 4096) return;
  int k = idx >> 12, col = idx & 4095;
  short b = f2bf(W[idx]);
  int gate = col >> 10, hidx = col & 1023;
  int g = hidx >> 3, off = hidx & 7;
  int pc = off * 4 + gate;
  if (k < 512) {
    WxP[(size_t)(((g * 64 + (k >> 3)) * 32 + pc) << 3) + (k & 7)] = b;
  } else {
    int kh = k - 512;
    WhP[(size_t)(((g * 128 + (kh >> 3)) * 32 + pc) << 3) + (kh & 7)] = b;
  }
}

// ---------------------------------------------------------------------------
// prep_x: x[t][m][k] f32 -> xbp[t][kb][m][8] bf16.
__global__ __launch_bounds__(256) void prep_x(const float* __restrict__ x,
                                              short* __restrict__ xbp) {
  int idx = blockIdx.x * 256 + threadIdx.x;
  if (idx >= SEQN * 64 * 64) return;
  int kb = idx & 63, m = (idx >> 6) & 63, t = idx >> 12;
  const float4* xp = reinterpret_cast<const float4*>(x + ((size_t)t * 64 + m) * 512 + kb * 8);
  float4 a = xp[0], c = xp[1];
  s16x8 v;
  v[0] = f2bf(a.x); v[1] = f2bf(a.y); v[2] = f2bf(a.z); v[3] = f2bf(a.w);
  v[4] = f2bf(c.x); v[5] = f2bf(c.y); v[6] = f2bf(c.z); v[7] = f2bf(c.w);
  reinterpret_cast<s16x8*>(xbp)[((size_t)t * 64 + kb) * 64 + m] = v;
}

// ---------------------------------------------------------------------------
// lstm_seq: 128 WGs x 256. WG g: hidden [8g,8g+8). Wave w: batch rows [16w,16w+16).
// Lane l: m = w*16+(l&15), q4 = l>>4, hidden cols c0 = 8g+q4, c1 = c0+4, all 4 gates.
// hq[t&3][gsrc 128][m 64][j 2] u64 = 4 bf16: j=0 -> cols 8gsrc+0..3, j=1 -> +4..7
//   (k-order: a dwordx4 [j0|j1] IS the MFMA B-frag for k-chunk gsrc).
// tagv[t&3][w 4][gsrc 128] u64 == t  <=>  producer (gsrc, wave w) h_{t-1} acked at LLC.
__global__ __launch_bounds__(256, 1) void lstm_seq(const short* __restrict__ xbp,
                                                   const short* __restrict__ WhP,
                                                   const short* __restrict__ WxP,
                                                   const float* __restrict__ bias,
                                                   const float* __restrict__ peep_i,
                                                   const float* __restrict__ peep_f,
                                                   const float* __restrict__ peep_o,
                                                   u64* hq,
                                                   u64* tagv,
                                                   float* __restrict__ out) {
  __shared__ short WhS[32768];   // 64KB [kb 128][pc 32][8]
  __shared__ short WxS[16384];   // 32KB [kb  64][pc 32][8]
  __shared__ float outS[512];    //  2KB
  int g = blockIdx.x;
  int tid = threadIdx.x, w = tid >> 6, l = tid & 63;
  {
    const s16x8* src = reinterpret_cast<const s16x8*>(WhP + (size_t)g * 32768);
    s16x8* dst = reinterpret_cast<s16x8*>(WhS);
#pragma unroll
    for (int i = 0; i < 16; ++i) dst[i * 256 + tid] = src[i * 256 + tid];
    const s16x8* src2 = reinterpret_cast<const s16x8*>(WxP + (size_t)g * 16384);
    s16x8* dst2 = reinterpret_cast<s16x8*>(WxS);
#pragma unroll
    for (int i = 0; i < 8; ++i) dst2[i * 256 + tid] = src2[i * 256 + tid];
  }
  int m = w * 16 + (l & 15), q4 = l >> 4, l15 = l & 15;
  int c0 = g * 8 + q4, c1 = c0 + 4;
  float bi0 = bias[c0], bj0 = bias[1024 + c0], bf0 = bias[2048 + c0], bo0 = bias[3072 + c0];
  float bi1 = bias[c1], bj1 = bias[1024 + c1], bf1 = bias[2048 + c1], bo1 = bias[3072 + c1];
  float pi0 = peep_i[c0], pf0 = peep_f[c0], po0 = peep_o[c0];
  float pi1 = peep_i[c1], pf1 = peep_f[c1], po1 = peep_o[c1];
  float cr0 = 0.f, cr1 = 0.f;
  s16x8* WhS16 = reinterpret_cast<s16x8*>(WhS);
  s16x8* WxS16 = reinterpret_cast<s16x8*>(WxS);
  __syncthreads();

// issue group G: 8 x dwordx4/lane (pure payload; each IS a B-frag), sc0 sc1 (LLC-fresh)
#define ISSUE(BANK, G)                                                                   \
  {                                                                                      \
    _Pragma("unroll") for (int i = 0; i < 8; ++i) {                                      \
      const u64* p_ = rdq + (size_t)((((G) * 8 + i) * 4 + q4) * 128 + m * 2);            \
      asm volatile("global_load_dwordx4 %0, %1, off sc0 sc1" : "=v"(BANK[i]) : "v"(p_)); \
    }                                                                                    \
  }
#define MFMAG(BANK, G)                                                                   \
  {                                                                                      \
    _Pragma("unroll") for (int i = 0; i < 8; ++i) {                                      \
      int kb_ = ((G) * 8 + i) * 4 + q4;                                                  \
      s16x8 bv;                                                                          \
      __builtin_memcpy(&bv, &BANK[i], 16);                                               \
      s16x8 a0 = WhS16[kb_ * 32 + l15];                                                  \
      s16x8 a1 = WhS16[kb_ * 32 + 16 + l15];                                             \
      acc0 = __builtin_amdgcn_mfma_f32_16x16x32_bf16(a0, bv, acc0, 0, 0, 0);             \
      acc1 = __builtin_amdgcn_mfma_f32_16x16x32_bf16(a1, bv, acc1, 0, 0, 0);             \
    }                                                                                    \
  }
#define VWAIT(N)                                                                         \
  asm volatile("s_waitcnt vmcnt(" #N ")" ::: "memory");                                  \
  __builtin_amdgcn_sched_barrier(0);

  for (int t = 0; t < SEQN; ++t) {
    f32x4 acc0 = {0.f, 0.f, 0.f, 0.f}, acc1 = {0.f, 0.f, 0.f, 0.f};
    // ---- x-projection (h-independent; overlaps other WGs' publish) ----
    {
      const s16x8* xt = reinterpret_cast<const s16x8*>(xbp) + (size_t)t * 4096;
#pragma unroll 4
      for (int kk = 0; kk < 16; ++kk) {
        int kb = kk * 4 + q4;
        s16x8 bx = xt[kb * 64 + m];
        s16x8 a0 = WxS16[kb * 32 + l15];
        s16x8 a1 = WxS16[kb * 32 + 16 + l15];
        acc0 = __builtin_amdgcn_mfma_f32_16x16x32_bf16(a0, bx, acc0, 0, 0, 0);
        acc1 = __builtin_amdgcn_mfma_f32_16x16x32_bf16(a1, bx, acc1, 0, 0, 0);
      }
    }
    if (t > 0) {
      // ---- GATE: this wave needs producer waves w (its rows) of all 128 WGs ----
      {
        const u64* gp = tagv + (size_t)(t & (DEPTH - 1)) * 512 + (size_t)w * 128 + 2 * l;
        int guard = 0;
        while (true) {
          i32x4 gv;
          asm volatile("global_load_dwordx4 %0, %1, off sc0 sc1" : "=v"(gv) : "v"(gp));
          asm volatile("s_waitcnt vmcnt(0)" ::: "memory");
          __builtin_amdgcn_sched_barrier(0);
          if (__all((int)((gv[0] == t) & (gv[2] == t)))) break;
          if (++guard > (1 << 13)) break;  // fail loud (wrong data), never hang
          __builtin_amdgcn_s_sleep(1);
        }
      }
      // ---- consume: single-shot loads, counted-vmcnt pipeline, no checks ----
      const u64* rdq = hq + (size_t)(t & (DEPTH - 1)) * 16384;
      i32x4 hA[8], hB[8];
      ISSUE(hA, 0);
      ISSUE(hB, 1);
      VWAIT(8);
      MFMAG(hA, 0);
      ISSUE(hA, 2);
      VWAIT(8);
      MFMAG(hB, 1);
      ISSUE(hB, 3);
      VWAIT(8);
      MFMAG(hA, 2);
      VWAIT(0);
      MFMAG(hB, 3);
    }
    // ---- elementwise (lane-local: all 4 gates of c0 and c1) ----
    float i0 = sigf(acc0[0] + bi0 + cr0 * pi0);
    float f0 = sigf(acc0[2] + bf0 + cr0 * pf0);
    float cn0 = f0 * cr0 + i0 * tanh_fast(acc0[1] + bj0);
    float o0 = sigf(acc0[3] + bo0 + cn0 * po0);
    float h0 = o0 * tanh_fast(cn0);
    cr0 = cn0;
    float i1 = sigf(acc1[0] + bi1 + cr1 * pi1);
    float f1 = sigf(acc1[2] + bf1 + cr1 * pf1);
    float cn1 = f1 * cr1 + i1 * tanh_fast(acc1[1] + bj1);
    float o1 = sigf(acc1[3] + bo1 + cn1 * po1);
    float h1 = o1 * tanh_fast(cn1);
    cr1 = cn1;
    // ---- publish: shfl-pack pure payload -> exchanges -> drain -> per-wave tag ----
    {
      unsigned myh = (unsigned)(unsigned short)f2bf(h0) |
                     ((unsigned)(unsigned short)f2bf(h1) << 16);
      int base = l15;
      unsigned va = (unsigned)__shfl((int)myh, base);
      unsigned vb = (unsigned)__shfl((int)myh, base + 16);
      unsigned vc = (unsigned)__shfl((int)myh, base + 32);
      unsigned vd = (unsigned)__shfl((int)myh, base + 48);
      if (q4 < 2) {
        u64 q;
        if (q4 == 0)  // j=0: h0 of lanes q4=0..3 = cols 8g+0..3 (k-order)
          q = (u64)(va & 0xFFFFu) | ((u64)(vb & 0xFFFFu) << 16) |
              ((u64)(vc & 0xFFFFu) << 32) | ((u64)(vd & 0xFFFFu) << 48);
        else          // j=1: h1 of lanes q4=0..3 = cols 8g+4..7
          q = (u64)(va >> 16) | ((u64)(vb >> 16) << 16) |
              ((u64)(vc >> 16) << 32) | ((u64)(vd >> 16) << 48);
        (void)__hip_atomic_exchange(
            hq + (size_t)((t + 1) & (DEPTH - 1)) * 16384 + g * 128 + m * 2 + q4, q,
            __ATOMIC_RELAXED, __HIP_MEMORY_SCOPE_AGENT);
      }
    }
    asm volatile("s_waitcnt vmcnt(0)" ::: "memory");  // payload acked at LLC
    if (l == 0)
      (void)__hip_atomic_exchange(
          tagv + (size_t)((t + 1) & (DEPTH - 1)) * 512 + (size_t)w * 128 + g,
          (u64)(unsigned)(t + 1), __ATOMIC_RELAXED, __HIP_MEMORY_SCOPE_AGENT);
    // ---- coalesced hidden_seq store via wave-local LDS stage (off critical path) ----
    outS[w * 128 + l15 * 8 + q4] = h0;
    outS[w * 128 + l15 * 8 + q4 + 4] = h1;
    {
      f32x2 v = *reinterpret_cast<f32x2*>(&outS[w * 128 + (l >> 2) * 8 + (l & 3) * 2]);
      int row = w * 16 + (l >> 2), col = g * 8 + (l & 3) * 2;
      __builtin_nontemporal_store(
          v, reinterpret_cast<f32x2*>(out + (size_t)t * 65536 + (size_t)row * 1024 + col));
    }
    if (t == SEQN - 1) {
      out[33554432ull + (size_t)m * 1024 + c0] = cn0;  // c_T
      out[33554432ull + (size_t)m * 1024 + c1] = cn1;
      out[33619968ull + (size_t)m * 1024 + c0] = h0;   // h_T
      out[33619968ull + (size_t)m * 1024 + c1] = h1;
    }
  }
#undef ISSUE
#undef MFMAG
#undef VWAIT
}

// ---------------------------------------------------------------------------
extern "C" void kernel_launch(void* const* d_in, const int* in_sizes, int n_in,
                              void* d_out, int out_size, void* d_ws, size_t ws_size,
                              hipStream_t stream) {
  const float* x      = (const float*)d_in[0];
  const float* W      = (const float*)d_in[1];
  const float* bias   = (const float*)d_in[2];
  const float* peep_i = (const float*)d_in[3];
  const float* peep_f = (const float*)d_in[4];
  const float* peep_o = (const float*)d_in[5];
  char* ws = (char*)d_ws;
  short* WxP = (short*)(ws);                   //  4194304 B
  short* WhP = (short*)(ws + 4194304ull);      //  8388608 B
  short* xbp = (short*)(ws + 12582912ull);     // 33554432 B
  u64* hq    = (u64*)(ws + 46137344ull);       //   524288 B (4 x 128KB pure-payload h)
  u64* tagv  = (u64*)(ws + 46661632ull);       //    16384 B (4 x 4KB per-wave tags)
  // zero tags every launch: stale tag values from a prior replay must never satisfy
  // this run's gate early (payload needs no memset: gate-pass implies this-run write)
  (void)hipMemsetAsync(tagv, 0, 16384ull, stream);
  prep_w<<<24576, 256, 0, stream>>>(W, WxP, WhP);
  prep_x<<<8192, 256, 0, stream>>>(x, xbp);
  lstm_seq<<<NWG, 256, 0, stream>>>(xbp, WhP, WxP, bias, peep_i, peep_f, peep_o, hq,
                                    tagv, (float*)d_out);
}